// Round 3
// baseline (262.785 us; speedup 1.0000x reference)
//
#include <hip/hip_runtime.h>
#include <hip/hip_bf16.h>
#include <stdint.h>

// ---------------------------------------------------------------------------
// LayerNormLSTMCell: B=4096, I=H=1024, 4H=4096
//  hi = LN(input @ w_i2h + b_i2h; g_i2h, be_i2h)        [B,4H]
//  hh = LN(h_prev @ w_h2h + b_h2h; g_h2h, be_h2h)       [B,4H]
//  i,f,u,o = split(hi+hh, 4)
//  c = LN(c_prev*sigm(f+1) + tanh(u)*sigm(i); g_c,be_c) [B,H]
//  h = sigm(o)*tanh(c)
// LN: mean, UNBIASED std (ddof=1), divide by (std + 1e-6)
// ---------------------------------------------------------------------------

#define BDIM 4096
#define KDIM 1024
#define NDIM 4096
#define EPSV 1e-6f

typedef float f32x4 __attribute__((ext_vector_type(4)));
typedef __bf16 bf16x8 __attribute__((ext_vector_type(8)));
typedef unsigned short u16x8 __attribute__((ext_vector_type(8)));

__device__ inline unsigned short f2bf(float f) {
    unsigned u = __builtin_bit_cast(unsigned, f);
    u += 0x7FFFu + ((u >> 16) & 1u);   // round-to-nearest-even
    return (unsigned short)(u >> 16);
}
__device__ inline float bf2f(unsigned short u) {
    return __builtin_bit_cast(float, (unsigned)u << 16);
}
__device__ inline float sigm(float x) {
    return 1.0f / (1.0f + __expf(-x));
}
// fast tanh: 1 - 2/(e^{2x}+1); saturates correctly at +-inf
__device__ inline float ftanh(float x) {
    return 1.0f - 2.0f / (__expf(2.0f * x) + 1.0f);
}

// async global->LDS, 16B per lane. lds ptr must be wave-uniform.
__device__ inline void async16(const unsigned short* g, unsigned short* lds) {
    __builtin_amdgcn_global_load_lds(
        (const __attribute__((address_space(1))) void*)g,
        (__attribute__((address_space(3))) void*)lds,
        16, 0, 0);
}

// ---------------------------------------------------------------------------
// prep: z=0/1 cast input/h_prev f32->bf16 (8 elem/thread, 16B stores)
//       z=2/3 transpose+cast w f32 [1024][4096] -> bf16 [4096][1024]
// ---------------------------------------------------------------------------
__global__ __launch_bounds__(256) void prep(
    const float* __restrict__ in0, unsigned short* __restrict__ o0,
    const float* __restrict__ in1, unsigned short* __restrict__ o1,
    const float* __restrict__ w0, unsigned short* __restrict__ w0T,
    const float* __restrict__ w1, unsigned short* __restrict__ w1T)
{
    __shared__ float tile[64][65];
    const int z = blockIdx.z, tid = threadIdx.x;
    if (z < 2) {
        const float* src = z ? in1 : in0;
        unsigned short* dst = z ? o1 : o0;
        int i = (blockIdx.x * 256 + tid) * 8;
        float4 a = *(const float4*)(src + i);
        float4 b = *(const float4*)(src + i + 4);
        u16x8 v;
        v[0] = f2bf(a.x); v[1] = f2bf(a.y); v[2] = f2bf(a.z); v[3] = f2bf(a.w);
        v[4] = f2bf(b.x); v[5] = f2bf(b.y); v[6] = f2bf(b.z); v[7] = f2bf(b.w);
        *(u16x8*)(dst + i) = v;
        return;
    }
    const int bx = blockIdx.x;
    if (bx >= (NDIM / 64) * (KDIM / 64)) return;
    const float* src = (z == 3) ? w1 : w0;
    unsigned short* dst = (z == 3) ? w1T : w0T;
    const int c0 = (bx & (NDIM / 64 - 1)) * 64;   // col in [0,4096)
    const int r0 = (bx >> 6) * 64;                // row in [0,1024)
    const int tx = tid & 63, ty = tid >> 6;       // 64 x 4
    #pragma unroll
    for (int i = 0; i < 64; i += 4)
        tile[ty + i][tx] = src[(size_t)(r0 + ty + i) * NDIM + c0 + tx];
    __syncthreads();
    #pragma unroll
    for (int p = 0; p < 2; ++p) {
        int c = p * 32 + (tid >> 3);
        int rs = (tid & 7) * 8;
        u16x8 v;
        #pragma unroll
        for (int j = 0; j < 8; ++j) v[j] = f2bf(tile[rs + j][c]);
        *(u16x8*)(dst + (size_t)(c0 + c) * KDIM + r0 + rs) = v;
    }
}

// ---------------------------------------------------------------------------
// GEMM: C[m][n] = sum_k A[m][k] * Bt[n][k] + bias[n]   (bf16 in, bf16 out)
// M=4096 N=4096 K=1024. 128x128 tile, BK=32, 4 waves, 4x4 16x16x32 MFMA/wave.
// LDS col-segment XOR swizzle on the GLOBAL source side of global_load_lds
// (undone on ds_read) -> conflict-free. Epilogue transposes through LDS so
// C is written with 16B contiguous ushort8 stores.
// blockIdx.z selects problem (i2h vs h2h).
// ---------------------------------------------------------------------------
__global__ __launch_bounds__(256) void gemm_bias_bf16(
    const unsigned short* __restrict__ A0, const unsigned short* __restrict__ B0,
    const float* __restrict__ bias0, unsigned short* __restrict__ C0,
    const unsigned short* __restrict__ A1, const unsigned short* __restrict__ B1,
    const float* __restrict__ bias1, unsigned short* __restrict__ C1)
{
    const unsigned short* A  = blockIdx.z ? A1 : A0;
    const unsigned short* Bt = blockIdx.z ? B1 : B0;
    const float* bias        = blockIdx.z ? bias1 : bias0;
    unsigned short* C        = blockIdx.z ? C1 : C0;

    // Als = SM[0..4095], Bls = SM[4096..8191]; epilogue reuses SM[0..4351]
    __shared__ __align__(16) unsigned short SM[8192];
    unsigned short* Als = SM;
    unsigned short* Bls = SM + 4096;

    const int tid  = threadIdx.x;
    const int wid  = tid >> 6;
    const int lane = tid & 63;
    const int bm = blockIdx.x, bn = blockIdx.y;

    const int wm = (wid >> 1) * 64;   // wave row offset in tile
    const int wn = (wid & 1) * 64;    // wave col offset in tile

    f32x4 acc[4][4] = {};

    // staging: row srow per 64-row half; global k-segment XOR-swizzled by row
    const int srow = wid * 16 + (lane >> 2);
    const int sseg = (lane & 3) ^ ((srow >> 1) & 3);
    const int scol = sseg * 8;
    const unsigned short* Abase = A  + (size_t)(bm * 128 + srow) * KDIM + scol;
    const unsigned short* Bbase = Bt + (size_t)(bn * 128 + srow) * KDIM + scol;
    unsigned short* AldsU = Als + wid * 512;   // wave-uniform, +lane*8 elems by HW
    unsigned short* BldsU = Bls + wid * 512;

    // fragment base pointers (undo swizzle)
    const int fseg = ((lane >> 4) ^ (((lane & 15) >> 1) & 3)) * 8;
    const unsigned short* a_ptr = &Als[(wm + (lane & 15)) * 32 + fseg];
    const unsigned short* b_ptr = &Bls[(wn + (lane & 15)) * 32 + fseg];

    for (int k0 = 0; k0 < KDIM; k0 += 32) {
        async16(Abase + k0,                     AldsU);
        async16(Abase + k0 + (size_t)64 * KDIM, AldsU + 2048);
        async16(Bbase + k0,                     BldsU);
        async16(Bbase + k0 + (size_t)64 * KDIM, BldsU + 2048);
        __syncthreads();

        bf16x8 af[4], bfv[4];
        #pragma unroll
        for (int mi = 0; mi < 4; ++mi) af[mi]  = *(const bf16x8*)(a_ptr + mi * 16 * 32);
        #pragma unroll
        for (int ni = 0; ni < 4; ++ni) bfv[ni] = *(const bf16x8*)(b_ptr + ni * 16 * 32);

        #pragma unroll
        for (int mi = 0; mi < 4; ++mi)
            #pragma unroll
            for (int ni = 0; ni < 4; ++ni)
                acc[mi][ni] = __builtin_amdgcn_mfma_f32_16x16x32_bf16(
                    af[mi], bfv[ni], acc[mi][ni], 0, 0, 0);
        __syncthreads();
    }

    // ---- epilogue: stage 32-row quarters through LDS, store ushort8 ----
    // D tile layout per lane: row=(lane>>4)*4+r, col=lane&15
    float bv[4];
    #pragma unroll
    for (int ni = 0; ni < 4; ++ni)
        bv[ni] = bias[bn * 128 + wn + ni * 16 + (lane & 15)];

    unsigned short* EP = SM;       // 32 x 136 ushorts = 8704 B
    #pragma unroll
    for (int q = 0; q < 4; ++q) {
        __syncthreads();
        if ((wid >> 1) == (q >> 1)) {
            #pragma unroll
            for (int b2 = 0; b2 < 2; ++b2) {
                int mi = (q & 1) * 2 + b2;
                #pragma unroll
                for (int r = 0; r < 4; ++r) {
                    int lrow = b2 * 16 + (lane >> 4) * 4 + r;
                    #pragma unroll
                    for (int ni = 0; ni < 4; ++ni)
                        EP[lrow * 136 + wn + ni * 16 + (lane & 15)] =
                            f2bf(acc[mi][ni][r] + bv[ni]);
                }
            }
        }
        __syncthreads();
        #pragma unroll
        for (int p = 0; p < 2; ++p) {
            int lrow = p * 16 + (tid >> 4);
            int cs = (tid & 15) * 8;
            u16x8 v = *(const u16x8*)(EP + lrow * 136 + cs);
            size_t grow = (size_t)(bm * 128 + q * 32 + lrow) * NDIM;
            *(u16x8*)(C + grow + bn * 128 + cs) = v;
        }
    }
}

// ---------------------------------------------------------------------------
// fused LN(hi)+LN(hh)+gates+LN(cell)+outputs. TWO rows per block:
// sub = tid>>7 selects row, t = tid&127 covers 8 cols per gate (16B loads).
// ---------------------------------------------------------------------------
__global__ __launch_bounds__(256) void ln_gates(
    const unsigned short* __restrict__ hi_pre, const unsigned short* __restrict__ hh_pre,
    const float* __restrict__ c_prev,
    const float* __restrict__ g1, const float* __restrict__ be1,
    const float* __restrict__ g2, const float* __restrict__ be2,
    const float* __restrict__ gc, const float* __restrict__ bec,
    float* __restrict__ h_out, float* __restrict__ c_out)
{
    __shared__ float sm[16];
    const int tid = threadIdx.x;
    const int sub = tid >> 7, t = tid & 127;
    const int wv = tid >> 6, lane = tid & 63;
    const int row = blockIdx.x * 2 + sub;
    const unsigned short* hir = hi_pre + (size_t)row * NDIM;
    const unsigned short* hhr = hh_pre + (size_t)row * NDIM;

    u16x8 vi[4], vh[4];
    float s1 = 0.f, ss1 = 0.f, s2 = 0.f, ss2 = 0.f;
    #pragma unroll
    for (int q = 0; q < 4; ++q) {
        int col = q * 1024 + t * 8;
        vi[q] = *(const u16x8*)(hir + col);
        vh[q] = *(const u16x8*)(hhr + col);
        #pragma unroll
        for (int j = 0; j < 8; ++j) {
            float a = bf2f(vi[q][j]), b = bf2f(vh[q][j]);
            s1 += a; ss1 += a * a; s2 += b; ss2 += b * b;
        }
    }
    #pragma unroll
    for (int off = 32; off > 0; off >>= 1) {
        s1 += __shfl_down(s1, off, 64);
        ss1 += __shfl_down(ss1, off, 64);
        s2 += __shfl_down(s2, off, 64);
        ss2 += __shfl_down(ss2, off, 64);
    }
    if (lane == 0) {
        sm[wv * 4 + 0] = s1; sm[wv * 4 + 1] = ss1;
        sm[wv * 4 + 2] = s2; sm[wv * 4 + 3] = ss2;
    }
    __syncthreads();
    const int base = sub * 8;
    float R1 = sm[base + 0] + sm[base + 4];
    float Q1 = sm[base + 1] + sm[base + 5];
    float R2 = sm[base + 2] + sm[base + 6];
    float Q2 = sm[base + 3] + sm[base + 7];

    const float n1 = (float)NDIM;
    float m1 = R1 / n1;
    float v1 = (Q1 - n1 * m1 * m1) / (n1 - 1.f);
    float r1 = 1.0f / (sqrtf(fmaxf(v1, 0.f)) + EPSV);
    float m2 = R2 / n1;
    float v2 = (Q2 - n1 * m2 * m2) / (n1 - 1.f);
    float r2 = 1.0f / (sqrtf(fmaxf(v2, 0.f)) + EPSV);

    float gate[4][8];
    #pragma unroll
    for (int q = 0; q < 4; ++q) {
        int col = q * 1024 + t * 8;
        float4 G1a = *(const float4*)(g1 + col),  G1b = *(const float4*)(g1 + col + 4);
        float4 B1a = *(const float4*)(be1 + col), B1b = *(const float4*)(be1 + col + 4);
        float4 G2a = *(const float4*)(g2 + col),  G2b = *(const float4*)(g2 + col + 4);
        float4 B2a = *(const float4*)(be2 + col), B2b = *(const float4*)(be2 + col + 4);
        float G1[8] = {G1a.x, G1a.y, G1a.z, G1a.w, G1b.x, G1b.y, G1b.z, G1b.w};
        float B1[8] = {B1a.x, B1a.y, B1a.z, B1a.w, B1b.x, B1b.y, B1b.z, B1b.w};
        float G2[8] = {G2a.x, G2a.y, G2a.z, G2a.w, G2b.x, G2b.y, G2b.z, G2b.w};
        float B2[8] = {B2a.x, B2a.y, B2a.z, B2a.w, B2b.x, B2b.y, B2b.z, B2b.w};
        #pragma unroll
        for (int j = 0; j < 8; ++j)
            gate[q][j] = G1[j] * (bf2f(vi[q][j]) - m1) * r1 + B1[j]
                       + G2[j] * (bf2f(vh[q][j]) - m2) * r2 + B2[j];
    }

    float4 cpa = *(const float4*)(c_prev + (size_t)row * 1024 + t * 8);
    float4 cpb = *(const float4*)(c_prev + (size_t)row * 1024 + t * 8 + 4);
    float cpv[8] = {cpa.x, cpa.y, cpa.z, cpa.w, cpb.x, cpb.y, cpb.z, cpb.w};
    float a[8];
    float s3 = 0.f, ss3 = 0.f;
    #pragma unroll
    for (int j = 0; j < 8; ++j) {
        a[j] = cpv[j] * sigm(gate[1][j] + 1.0f) + ftanh(gate[2][j]) * sigm(gate[0][j]);
        s3 += a[j]; ss3 += a[j] * a[j];
    }
    #pragma unroll
    for (int off = 32; off > 0; off >>= 1) {
        s3 += __shfl_down(s3, off, 64);
        ss3 += __shfl_down(ss3, off, 64);
    }
    __syncthreads();   // sm reuse
    if (lane == 0) { sm[wv * 2 + 0] = s3; sm[wv * 2 + 1] = ss3; }
    __syncthreads();
    const int b2 = sub * 4;
    float R3 = sm[b2 + 0] + sm[b2 + 2];
    float Q3 = sm[b2 + 1] + sm[b2 + 3];
    const float n3 = 1024.f;
    float m3 = R3 / n3;
    float v3 = (Q3 - n3 * m3 * m3) / (n3 - 1.f);
    float r3 = 1.0f / (sqrtf(fmaxf(v3, 0.f)) + EPSV);

    int colh = t * 8;
    float4 GCa = *(const float4*)(gc + colh),  GCb = *(const float4*)(gc + colh + 4);
    float4 BCa = *(const float4*)(bec + colh), BCb = *(const float4*)(bec + colh + 4);
    float GC[8] = {GCa.x, GCa.y, GCa.z, GCa.w, GCb.x, GCb.y, GCb.z, GCb.w};
    float BC[8] = {BCa.x, BCa.y, BCa.z, BCa.w, BCb.x, BCb.y, BCb.z, BCb.w};
    float cj[8], hj[8];
    #pragma unroll
    for (int j = 0; j < 8; ++j) {
        cj[j] = GC[j] * (a[j] - m3) * r3 + BC[j];
        hj[j] = sigm(gate[3][j]) * ftanh(cj[j]);
    }
    float4 hva = {hj[0], hj[1], hj[2], hj[3]}, hvb = {hj[4], hj[5], hj[6], hj[7]};
    float4 cva = {cj[0], cj[1], cj[2], cj[3]}, cvb = {cj[4], cj[5], cj[6], cj[7]};
    *(float4*)(h_out + (size_t)row * 1024 + colh) = hva;
    *(float4*)(h_out + (size_t)row * 1024 + colh + 4) = hvb;
    *(float4*)(c_out + (size_t)row * 1024 + colh) = cva;
    *(float4*)(c_out + (size_t)row * 1024 + colh + 4) = cvb;
}

// ---------------------------------------------------------------------------
extern "C" void kernel_launch(void* const* d_in, const int* in_sizes, int n_in,
                              void* d_out, int out_size, void* d_ws, size_t ws_size,
                              hipStream_t stream) {
    const float* input  = (const float*)d_in[0];
    const float* h_prev = (const float*)d_in[1];
    const float* c_prev = (const float*)d_in[2];
    const float* w_i2h  = (const float*)d_in[3];
    const float* b_i2h  = (const float*)d_in[4];
    const float* w_h2h  = (const float*)d_in[5];
    const float* b_h2h  = (const float*)d_in[6];
    const float* g_i2h  = (const float*)d_in[7];
    const float* be_i2h = (const float*)d_in[8];
    const float* g_h2h  = (const float*)d_in[9];
    const float* be_h2h = (const float*)d_in[10];
    const float* g_c    = (const float*)d_in[11];
    const float* be_c   = (const float*)d_in[12];

    const size_t MK = (size_t)BDIM * KDIM;       // 4M
    const size_t MN = (size_t)BDIM * NDIM;       // 16M

    unsigned short* inA    = (unsigned short*)d_ws;
    unsigned short* inH    = inA + MK;
    unsigned short* w1T    = inH + MK;           // [N][K]
    unsigned short* w2T    = w1T + MK;
    unsigned short* hi_pre = w2T + MK;           // [B][4H] bf16
    unsigned short* hh_pre = hi_pre + MN;        // total 96 MB

    float* h_out = (float*)d_out;
    float* c_out = h_out + (size_t)BDIM * 1024;

    prep<<<dim3(2048, 1, 4), 256, 0, stream>>>(
        input, inA, h_prev, inH, w_i2h, w1T, w_h2h, w2T);

    gemm_bias_bf16<<<dim3(32, 32, 2), 256, 0, stream>>>(
        inA, w1T, b_i2h, hi_pre, inH, w2T, b_h2h, hh_pre);

    ln_gates<<<2048, 256, 0, stream>>>(
        hi_pre, hh_pre, c_prev, g_i2h, be_i2h, g_h2h, be_h2h, g_c, be_c, h_out, c_out);
}

// Round 4
// 252.698 us; speedup vs baseline: 1.0399x; 1.0399x over previous
//
#include <hip/hip_runtime.h>
#include <hip/hip_bf16.h>
#include <stdint.h>

// ---------------------------------------------------------------------------
// LayerNormLSTMCell: B=4096, I=H=1024, 4H=4096
//  hi = LN(input @ w_i2h + b_i2h; g_i2h, be_i2h)        [B,4H]
//  hh = LN(h_prev @ w_h2h + b_h2h; g_h2h, be_h2h)       [B,4H]
//  i,f,u,o = split(hi+hh, 4)
//  c = LN(c_prev*sigm(f+1) + tanh(u)*sigm(i); g_c,be_c) [B,H]
//  h = sigm(o)*tanh(c)
// LN: mean, UNBIASED std (ddof=1), divide by (std + 1e-6)
// ---------------------------------------------------------------------------

#define BDIM 4096
#define KDIM 1024
#define NDIM 4096
#define EPSV 1e-6f

typedef float f32x4 __attribute__((ext_vector_type(4)));
typedef __bf16 bf16x8 __attribute__((ext_vector_type(8)));
typedef unsigned short u16x8 __attribute__((ext_vector_type(8)));

__device__ inline unsigned short f2bf(float f) {
    unsigned u = __builtin_bit_cast(unsigned, f);
    u += 0x7FFFu + ((u >> 16) & 1u);   // round-to-nearest-even
    return (unsigned short)(u >> 16);
}
__device__ inline float bf2f(unsigned short u) {
    return __builtin_bit_cast(float, (unsigned)u << 16);
}
__device__ inline float sigm(float x) {
    return 1.0f / (1.0f + __expf(-x));
}
// fast tanh: 1 - 2/(e^{2x}+1); saturates correctly at +-inf
__device__ inline float ftanh(float x) {
    return 1.0f - 2.0f / (__expf(2.0f * x) + 1.0f);
}

// async global->LDS, 16B per lane. lds ptr must be wave-uniform.
__device__ inline void async16(const unsigned short* g, unsigned short* lds) {
    __builtin_amdgcn_global_load_lds(
        (const __attribute__((address_space(1))) void*)g,
        (__attribute__((address_space(3))) void*)lds,
        16, 0, 0);
}

// ---------------------------------------------------------------------------
// prep: z=0/1 cast input/h_prev f32->bf16 (8 elem/thread, 16B stores)
//       z=2/3 transpose+cast w f32 [1024][4096] -> bf16 [4096][1024]
// ---------------------------------------------------------------------------
__global__ __launch_bounds__(256) void prep(
    const float* __restrict__ in0, unsigned short* __restrict__ o0,
    const float* __restrict__ in1, unsigned short* __restrict__ o1,
    const float* __restrict__ w0, unsigned short* __restrict__ w0T,
    const float* __restrict__ w1, unsigned short* __restrict__ w1T)
{
    __shared__ float tile[64][65];
    const int z = blockIdx.z, tid = threadIdx.x;
    if (z < 2) {
        const float* src = z ? in1 : in0;
        unsigned short* dst = z ? o1 : o0;
        int i = (blockIdx.x * 256 + tid) * 8;
        float4 a = *(const float4*)(src + i);
        float4 b = *(const float4*)(src + i + 4);
        u16x8 v;
        v[0] = f2bf(a.x); v[1] = f2bf(a.y); v[2] = f2bf(a.z); v[3] = f2bf(a.w);
        v[4] = f2bf(b.x); v[5] = f2bf(b.y); v[6] = f2bf(b.z); v[7] = f2bf(b.w);
        *(u16x8*)(dst + i) = v;
        return;
    }
    const int bx = blockIdx.x;
    if (bx >= (NDIM / 64) * (KDIM / 64)) return;
    const float* src = (z == 3) ? w1 : w0;
    unsigned short* dst = (z == 3) ? w1T : w0T;
    const int c0 = (bx & (NDIM / 64 - 1)) * 64;   // col in [0,4096)
    const int r0 = (bx >> 6) * 64;                // row in [0,1024)
    const int tx = tid & 63, ty = tid >> 6;       // 64 x 4
    #pragma unroll
    for (int i = 0; i < 64; i += 4)
        tile[ty + i][tx] = src[(size_t)(r0 + ty + i) * NDIM + c0 + tx];
    __syncthreads();
    #pragma unroll
    for (int p = 0; p < 2; ++p) {
        int c = p * 32 + (tid >> 3);
        int rs = (tid & 7) * 8;
        u16x8 v;
        #pragma unroll
        for (int j = 0; j < 8; ++j) v[j] = f2bf(tile[rs + j][c]);
        *(u16x8*)(dst + (size_t)(c0 + c) * KDIM + r0 + rs) = v;
    }
}

// ---------------------------------------------------------------------------
// GEMM: C[m][n] = sum_k A[m][k] * Bt[n][k] + bias[n]   (bf16 in, bf16 out)
// M=4096 N=4096 K=1024. 128x128 tile, BK=64 (one barrier pair per 64 k),
// 4 waves, 4x4 16x16x32 MFMA/wave, 2 k-segments per iter.
// 8-way LDS segment XOR swizzle (phys = log ^ (row&7)) applied on the GLOBAL
// source side of global_load_lds, undone on ds_read -> 2-way only (free).
// Supertile remap: bands of 8 bm x 32 bn so each XCD keeps one A-row band
// L2-resident. blockIdx.z selects problem (i2h vs h2h).
// ---------------------------------------------------------------------------
__global__ __launch_bounds__(256) void gemm_bias_bf16(
    const unsigned short* __restrict__ A0, const unsigned short* __restrict__ B0,
    const float* __restrict__ bias0, unsigned short* __restrict__ C0,
    const unsigned short* __restrict__ A1, const unsigned short* __restrict__ B1,
    const float* __restrict__ bias1, unsigned short* __restrict__ C1)
{
    const unsigned short* A  = blockIdx.z ? A1 : A0;
    const unsigned short* Bt = blockIdx.z ? B1 : B0;
    const float* bias        = blockIdx.z ? bias1 : bias0;
    unsigned short* C        = blockIdx.z ? C1 : C0;

    __shared__ __align__(16) unsigned short Als[128 * 64];   // 16 KB
    __shared__ __align__(16) unsigned short Bls[128 * 64];   // 16 KB

    const int tid  = threadIdx.x;
    const int wid  = tid >> 6;
    const int lane = tid & 63;

    // supertile remap: gid 0..1023 -> band of 8 bm x 32 bn
    const int gid    = blockIdx.y * 32 + blockIdx.x;
    const int band   = gid >> 8;
    const int within = gid & 255;
    const int bm = band * 8 + (within & 7);
    const int bn = within >> 3;

    const int wm = (wid >> 1) * 64;   // wave row offset in tile
    const int wn = (wid & 1) * 64;    // wave col offset in tile

    f32x4 acc[4][4] = {};

    // ---- staging addressing (BK=64: row = i*32 + wid*8 + lane/8) ----
    // logical seg = (lane&7) ^ (lane>>3)  [since row&7 == lane>>3]
    const int sseg = (lane & 7) ^ (lane >> 3);
    const unsigned short* Abase =
        A + (size_t)(bm * 128 + wid * 8 + (lane >> 3)) * KDIM + sseg * 8;
    const unsigned short* Bbase =
        Bt + (size_t)(bn * 128 + wid * 8 + (lane >> 3)) * KDIM + sseg * 8;
    unsigned short* AldsU = Als + (wid * 8) * 64;   // wave-uniform
    unsigned short* BldsU = Bls + (wid * 8) * 64;

    // ---- fragment pointers (undo swizzle) ----
    // frag row = wm/wn + mi*16 + (lane&15); row&7 = lane&7
    // logical k-seg = kseg*4 + (lane>>4); phys = logical ^ (lane&7)
    const int q  = lane >> 4;
    const int r7 = lane & 7;
    const int frow = lane & 15;
    const int ph0 = ((q ^ r7)) * 8;        // kseg 0
    const int ph1 = ((q ^ r7) ^ 4) * 8;    // kseg 1
    const unsigned short* aP0 = &Als[(wm + frow) * 64 + ph0];
    const unsigned short* aP1 = &Als[(wm + frow) * 64 + ph1];
    const unsigned short* bP0 = &Bls[(wn + frow) * 64 + ph0];
    const unsigned short* bP1 = &Bls[(wn + frow) * 64 + ph1];

    for (int k0 = 0; k0 < KDIM; k0 += 64) {
        #pragma unroll
        for (int i = 0; i < 4; ++i) {
            async16(Abase + k0 + (size_t)(i * 32) * KDIM, AldsU + i * 32 * 64);
            async16(Bbase + k0 + (size_t)(i * 32) * KDIM, BldsU + i * 32 * 64);
        }
        __syncthreads();

        bf16x8 af[4], bfv[4];
        // k-segment 0
        #pragma unroll
        for (int mi = 0; mi < 4; ++mi) af[mi]  = *(const bf16x8*)(aP0 + mi * 16 * 64);
        #pragma unroll
        for (int ni = 0; ni < 4; ++ni) bfv[ni] = *(const bf16x8*)(bP0 + ni * 16 * 64);
        #pragma unroll
        for (int mi = 0; mi < 4; ++mi)
            #pragma unroll
            for (int ni = 0; ni < 4; ++ni)
                acc[mi][ni] = __builtin_amdgcn_mfma_f32_16x16x32_bf16(
                    af[mi], bfv[ni], acc[mi][ni], 0, 0, 0);
        // k-segment 1
        #pragma unroll
        for (int mi = 0; mi < 4; ++mi) af[mi]  = *(const bf16x8*)(aP1 + mi * 16 * 64);
        #pragma unroll
        for (int ni = 0; ni < 4; ++ni) bfv[ni] = *(const bf16x8*)(bP1 + ni * 16 * 64);
        #pragma unroll
        for (int mi = 0; mi < 4; ++mi)
            #pragma unroll
            for (int ni = 0; ni < 4; ++ni)
                acc[mi][ni] = __builtin_amdgcn_mfma_f32_16x16x32_bf16(
                    af[mi], bfv[ni], acc[mi][ni], 0, 0, 0);

        __syncthreads();
    }

    // epilogue (R2-proven): lane holds D[row=(lane>>4)*4+r][col=lane&15]
    const int rb = wm + (lane >> 4) * 4;
    const int cb = wn + (lane & 15);
    float bv[4];
    #pragma unroll
    for (int ni = 0; ni < 4; ++ni) bv[ni] = bias[bn * 128 + cb + ni * 16];
    #pragma unroll
    for (int mi = 0; mi < 4; ++mi) {
        #pragma unroll
        for (int r = 0; r < 4; ++r) {
            size_t grow = (size_t)(bm * 128 + rb + mi * 16 + r) * NDIM;
            #pragma unroll
            for (int ni = 0; ni < 4; ++ni)
                C[grow + bn * 128 + cb + ni * 16] = f2bf(acc[mi][ni][r] + bv[ni]);
        }
    }
}

// ---------------------------------------------------------------------------
// fused LN(hi)+LN(hh)+gates+LN(cell)+outputs. TWO rows per block:
// sub = tid>>7 selects row, t = tid&127 covers 8 cols per gate (16B loads).
// ---------------------------------------------------------------------------
__global__ __launch_bounds__(256) void ln_gates(
    const unsigned short* __restrict__ hi_pre, const unsigned short* __restrict__ hh_pre,
    const float* __restrict__ c_prev,
    const float* __restrict__ g1, const float* __restrict__ be1,
    const float* __restrict__ g2, const float* __restrict__ be2,
    const float* __restrict__ gc, const float* __restrict__ bec,
    float* __restrict__ h_out, float* __restrict__ c_out)
{
    __shared__ float sm[16];
    const int tid = threadIdx.x;
    const int sub = tid >> 7, t = tid & 127;
    const int wv = tid >> 6, lane = tid & 63;
    const int row = blockIdx.x * 2 + sub;
    const unsigned short* hir = hi_pre + (size_t)row * NDIM;
    const unsigned short* hhr = hh_pre + (size_t)row * NDIM;

    u16x8 vi[4], vh[4];
    float s1 = 0.f, ss1 = 0.f, s2 = 0.f, ss2 = 0.f;
    #pragma unroll
    for (int q = 0; q < 4; ++q) {
        int col = q * 1024 + t * 8;
        vi[q] = *(const u16x8*)(hir + col);
        vh[q] = *(const u16x8*)(hhr + col);
        #pragma unroll
        for (int j = 0; j < 8; ++j) {
            float a = bf2f(vi[q][j]), b = bf2f(vh[q][j]);
            s1 += a; ss1 += a * a; s2 += b; ss2 += b * b;
        }
    }
    #pragma unroll
    for (int off = 32; off > 0; off >>= 1) {
        s1 += __shfl_down(s1, off, 64);
        ss1 += __shfl_down(ss1, off, 64);
        s2 += __shfl_down(s2, off, 64);
        ss2 += __shfl_down(ss2, off, 64);
    }
    if (lane == 0) {
        sm[wv * 4 + 0] = s1; sm[wv * 4 + 1] = ss1;
        sm[wv * 4 + 2] = s2; sm[wv * 4 + 3] = ss2;
    }
    __syncthreads();
    const int base = sub * 8;
    float R1 = sm[base + 0] + sm[base + 4];
    float Q1 = sm[base + 1] + sm[base + 5];
    float R2 = sm[base + 2] + sm[base + 6];
    float Q2 = sm[base + 3] + sm[base + 7];

    const float n1 = (float)NDIM;
    float m1 = R1 / n1;
    float v1 = (Q1 - n1 * m1 * m1) / (n1 - 1.f);
    float r1 = 1.0f / (sqrtf(fmaxf(v1, 0.f)) + EPSV);
    float m2 = R2 / n1;
    float v2 = (Q2 - n1 * m2 * m2) / (n1 - 1.f);
    float r2 = 1.0f / (sqrtf(fmaxf(v2, 0.f)) + EPSV);

    float gate[4][8];
    #pragma unroll
    for (int q = 0; q < 4; ++q) {
        int col = q * 1024 + t * 8;
        float4 G1a = *(const float4*)(g1 + col),  G1b = *(const float4*)(g1 + col + 4);
        float4 B1a = *(const float4*)(be1 + col), B1b = *(const float4*)(be1 + col + 4);
        float4 G2a = *(const float4*)(g2 + col),  G2b = *(const float4*)(g2 + col + 4);
        float4 B2a = *(const float4*)(be2 + col), B2b = *(const float4*)(be2 + col + 4);
        float G1[8] = {G1a.x, G1a.y, G1a.z, G1a.w, G1b.x, G1b.y, G1b.z, G1b.w};
        float B1[8] = {B1a.x, B1a.y, B1a.z, B1a.w, B1b.x, B1b.y, B1b.z, B1b.w};
        float G2[8] = {G2a.x, G2a.y, G2a.z, G2a.w, G2b.x, G2b.y, G2b.z, G2b.w};
        float B2[8] = {B2a.x, B2a.y, B2a.z, B2a.w, B2b.x, B2b.y, B2b.z, B2b.w};
        #pragma unroll
        for (int j = 0; j < 8; ++j)
            gate[q][j] = G1[j] * (bf2f(vi[q][j]) - m1) * r1 + B1[j]
                       + G2[j] * (bf2f(vh[q][j]) - m2) * r2 + B2[j];
    }

    float4 cpa = *(const float4*)(c_prev + (size_t)row * 1024 + t * 8);
    float4 cpb = *(const float4*)(c_prev + (size_t)row * 1024 + t * 8 + 4);
    float cpv[8] = {cpa.x, cpa.y, cpa.z, cpa.w, cpb.x, cpb.y, cpb.z, cpb.w};
    float a[8];
    float s3 = 0.f, ss3 = 0.f;
    #pragma unroll
    for (int j = 0; j < 8; ++j) {
        a[j] = cpv[j] * sigm(gate[1][j] + 1.0f) + ftanh(gate[2][j]) * sigm(gate[0][j]);
        s3 += a[j]; ss3 += a[j] * a[j];
    }
    #pragma unroll
    for (int off = 32; off > 0; off >>= 1) {
        s3 += __shfl_down(s3, off, 64);
        ss3 += __shfl_down(ss3, off, 64);
    }
    __syncthreads();   // sm reuse
    if (lane == 0) { sm[wv * 2 + 0] = s3; sm[wv * 2 + 1] = ss3; }
    __syncthreads();
    const int b2 = sub * 4;
    float R3 = sm[b2 + 0] + sm[b2 + 2];
    float Q3 = sm[b2 + 1] + sm[b2 + 3];
    const float n3 = 1024.f;
    float m3 = R3 / n3;
    float v3 = (Q3 - n3 * m3 * m3) / (n3 - 1.f);
    float r3 = 1.0f / (sqrtf(fmaxf(v3, 0.f)) + EPSV);

    int colh = t * 8;
    float4 GCa = *(const float4*)(gc + colh),  GCb = *(const float4*)(gc + colh + 4);
    float4 BCa = *(const float4*)(bec + colh), BCb = *(const float4*)(bec + colh + 4);
    float GC[8] = {GCa.x, GCa.y, GCa.z, GCa.w, GCb.x, GCb.y, GCb.z, GCb.w};
    float BC[8] = {BCa.x, BCa.y, BCa.z, BCa.w, BCb.x, BCb.y, BCb.z, BCb.w};
    float cj[8], hj[8];
    #pragma unroll
    for (int j = 0; j < 8; ++j) {
        cj[j] = GC[j] * (a[j] - m3) * r3 + BC[j];
        hj[j] = sigm(gate[3][j]) * ftanh(cj[j]);
    }
    float4 hva = {hj[0], hj[1], hj[2], hj[3]}, hvb = {hj[4], hj[5], hj[6], hj[7]};
    float4 cva = {cj[0], cj[1], cj[2], cj[3]}, cvb = {cj[4], cj[5], cj[6], cj[7]};
    *(float4*)(h_out + (size_t)row * 1024 + colh) = hva;
    *(float4*)(h_out + (size_t)row * 1024 + colh + 4) = hvb;
    *(float4*)(c_out + (size_t)row * 1024 + colh) = cva;
    *(float4*)(c_out + (size_t)row * 1024 + colh + 4) = cvb;
}

// ---------------------------------------------------------------------------
extern "C" void kernel_launch(void* const* d_in, const int* in_sizes, int n_in,
                              void* d_out, int out_size, void* d_ws, size_t ws_size,
                              hipStream_t stream) {
    const float* input  = (const float*)d_in[0];
    const float* h_prev = (const float*)d_in[1];
    const float* c_prev = (const float*)d_in[2];
    const float* w_i2h  = (const float*)d_in[3];
    const float* b_i2h  = (const float*)d_in[4];
    const float* w_h2h  = (const float*)d_in[5];
    const float* b_h2h  = (const float*)d_in[6];
    const float* g_i2h  = (const float*)d_in[7];
    const float* be_i2h = (const float*)d_in[8];
    const float* g_h2h  = (const float*)d_in[9];
    const float* be_h2h = (const float*)d_in[10];
    const float* g_c    = (const float*)d_in[11];
    const float* be_c   = (const float*)d_in[12];

    const size_t MK = (size_t)BDIM * KDIM;       // 4M
    const size_t MN = (size_t)BDIM * NDIM;       // 16M

    unsigned short* inA    = (unsigned short*)d_ws;
    unsigned short* inH    = inA + MK;
    unsigned short* w1T    = inH + MK;           // [N][K]
    unsigned short* w2T    = w1T + MK;
    unsigned short* hi_pre = w2T + MK;           // [B][4H] bf16
    unsigned short* hh_pre = hi_pre + MN;        // total 96 MB

    float* h_out = (float*)d_out;
    float* c_out = h_out + (size_t)BDIM * 1024;

    prep<<<dim3(2048, 1, 4), 256, 0, stream>>>(
        input, inA, h_prev, inH, w_i2h, w1T, w_h2h, w2T);

    gemm_bias_bf16<<<dim3(32, 32, 2), 256, 0, stream>>>(
        inA, w1T, b_i2h, hi_pre, inH, w2T, b_h2h, hh_pre);

    ln_gates<<<2048, 256, 0, stream>>>(
        hi_pre, hh_pre, c_prev, g_i2h, be_i2h, g_h2h, be_h2h, g_c, be_c, h_out, c_out);
}

// Round 5
// 244.992 us; speedup vs baseline: 1.0726x; 1.0315x over previous
//
#include <hip/hip_runtime.h>
#include <hip/hip_bf16.h>
#include <stdint.h>

// ---------------------------------------------------------------------------
// LayerNormLSTMCell: B=4096, I=H=1024, 4H=4096
//  hi = LN(input @ w_i2h + b_i2h; g_i2h, be_i2h)        [B,4H]
//  hh = LN(h_prev @ w_h2h + b_h2h; g_h2h, be_h2h)       [B,4H]
//  i,f,u,o = split(hi+hh, 4)
//  c = LN(c_prev*sigm(f+1) + tanh(u)*sigm(i); g_c,be_c) [B,H]
//  h = sigm(o)*tanh(c)
// LN: mean, UNBIASED std (ddof=1), divide by (std + 1e-6)
// ---------------------------------------------------------------------------

#define BDIM 4096
#define KDIM 1024
#define NDIM 4096
#define EPSV 1e-6f

typedef float f32x4 __attribute__((ext_vector_type(4)));
typedef float f32x16 __attribute__((ext_vector_type(16)));
typedef __bf16 bf16x8 __attribute__((ext_vector_type(8)));
typedef unsigned short u16x8 __attribute__((ext_vector_type(8)));

__device__ inline unsigned short f2bf(float f) {
    unsigned u = __builtin_bit_cast(unsigned, f);
    u += 0x7FFFu + ((u >> 16) & 1u);   // round-to-nearest-even
    return (unsigned short)(u >> 16);
}
__device__ inline float bf2f(unsigned short u) {
    return __builtin_bit_cast(float, (unsigned)u << 16);
}
__device__ inline float sigm(float x) {
    return 1.0f / (1.0f + __expf(-x));
}
// fast tanh: 1 - 2/(e^{2x}+1); saturates correctly at +-inf
__device__ inline float ftanh(float x) {
    return 1.0f - 2.0f / (__expf(2.0f * x) + 1.0f);
}

// async global->LDS, 16B per lane. lds ptr must be wave-uniform.
__device__ inline void async16(const unsigned short* g, unsigned short* lds) {
    __builtin_amdgcn_global_load_lds(
        (const __attribute__((address_space(1))) void*)g,
        (__attribute__((address_space(3))) void*)lds,
        16, 0, 0);
}

// ---------------------------------------------------------------------------
// prep: z=0/1 cast input/h_prev f32->bf16 (8 elem/thread, 16B stores)
//       z=2/3 transpose+cast w f32 [1024][4096] -> bf16 [4096][1024]
// ---------------------------------------------------------------------------
__global__ __launch_bounds__(256) void prep(
    const float* __restrict__ in0, unsigned short* __restrict__ o0,
    const float* __restrict__ in1, unsigned short* __restrict__ o1,
    const float* __restrict__ w0, unsigned short* __restrict__ w0T,
    const float* __restrict__ w1, unsigned short* __restrict__ w1T)
{
    __shared__ float tile[64][65];
    const int z = blockIdx.z, tid = threadIdx.x;
    if (z < 2) {
        const float* src = z ? in1 : in0;
        unsigned short* dst = z ? o1 : o0;
        int i = (blockIdx.x * 256 + tid) * 8;
        float4 a = *(const float4*)(src + i);
        float4 b = *(const float4*)(src + i + 4);
        u16x8 v;
        v[0] = f2bf(a.x); v[1] = f2bf(a.y); v[2] = f2bf(a.z); v[3] = f2bf(a.w);
        v[4] = f2bf(b.x); v[5] = f2bf(b.y); v[6] = f2bf(b.z); v[7] = f2bf(b.w);
        *(u16x8*)(dst + i) = v;
        return;
    }
    const int bx = blockIdx.x;
    if (bx >= (NDIM / 64) * (KDIM / 64)) return;
    const float* src = (z == 3) ? w1 : w0;
    unsigned short* dst = (z == 3) ? w1T : w0T;
    const int c0 = (bx & (NDIM / 64 - 1)) * 64;   // col in [0,4096)
    const int r0 = (bx >> 6) * 64;                // row in [0,1024)
    const int tx = tid & 63, ty = tid >> 6;       // 64 x 4
    #pragma unroll
    for (int i = 0; i < 64; i += 4)
        tile[ty + i][tx] = src[(size_t)(r0 + ty + i) * NDIM + c0 + tx];
    __syncthreads();
    #pragma unroll
    for (int p = 0; p < 2; ++p) {
        int c = p * 32 + (tid >> 3);
        int rs = (tid & 7) * 8;
        u16x8 v;
        #pragma unroll
        for (int j = 0; j < 8; ++j) v[j] = f2bf(tile[rs + j][c]);
        *(u16x8*)(dst + (size_t)(c0 + c) * KDIM + r0 + rs) = v;
    }
}

// ---------------------------------------------------------------------------
// GEMM: C[m][n] = sum_k A[m][k] * Bt[n][k] + bias[n]   (bf16 in, bf16 out)
// M=4096 N=4096 K=1024. Block tile 256x128, BK=64, 4 waves in 2x2 grid,
// wave-tile 128x64 via 4x2 of 32x32x16 MFMA (acc 128 VGPRs/lane).
// LDS: A 32KB + B 16KB. 8-seg XOR swizzle (phys = log ^ (row&7)) applied on
// the GLOBAL source side of global_load_lds, undone on ds_read -> uniform
// bank distribution (conflict-free, R2/R4-verified family).
// blockIdx.z selects problem (i2h vs h2h).
// ---------------------------------------------------------------------------
__global__ __launch_bounds__(256, 2) void gemm_bias_bf16(
    const unsigned short* __restrict__ A0, const unsigned short* __restrict__ B0,
    const float* __restrict__ bias0, unsigned short* __restrict__ C0,
    const unsigned short* __restrict__ A1, const unsigned short* __restrict__ B1,
    const float* __restrict__ bias1, unsigned short* __restrict__ C1)
{
    const unsigned short* A  = blockIdx.z ? A1 : A0;
    const unsigned short* Bt = blockIdx.z ? B1 : B0;
    const float* bias        = blockIdx.z ? bias1 : bias0;
    unsigned short* C        = blockIdx.z ? C1 : C0;

    __shared__ __align__(16) unsigned short Als[256 * 64];   // 32 KB
    __shared__ __align__(16) unsigned short Bls[128 * 64];   // 16 KB

    const int tid  = threadIdx.x;
    const int wid  = tid >> 6;
    const int lane = tid & 63;
    const int bm = blockIdx.x;      // 0..15 (256-row tiles)
    const int bn = blockIdx.y;      // 0..31 (128-col tiles)

    const int wr = wid >> 1;        // wave row: 0/1 -> rows wr*128
    const int wc = wid & 1;         // wave col: 0/1 -> cols wc*64

    f32x16 acc[4][2] = {};

    // ---- staging: call covers 32 rows (8/wave); row = base + (lane>>3),
    // seg = lane&7; global k-seg XOR-swizzled: sseg = (lane&7)^(row&7) ----
    const int sseg = (lane & 7) ^ (lane >> 3);
    const unsigned short* Abase =
        A + (size_t)(bm * 256 + wid * 8 + (lane >> 3)) * KDIM + sseg * 8;
    const unsigned short* Bbase =
        Bt + (size_t)(bn * 128 + wid * 8 + (lane >> 3)) * KDIM + sseg * 8;
    unsigned short* AldsU = Als + (wid * 8) * 64;   // wave-uniform
    unsigned short* BldsU = Bls + (wid * 8) * 64;

    // ---- fragment addressing (32x32x16): A[m=lane&31][k=(lane>>5)*8+j].
    // row = wr*128 + mi*32 + (lane&31); log k-seg = t*2 + (lane>>5);
    // phys = log ^ (row&7) = log ^ (lane&7) ----
    const int hi  = lane >> 5;
    const int r7  = lane & 7;
    const int m31 = lane & 31;
    const unsigned short* aRow[4];
    const unsigned short* bRow[2];
    #pragma unroll
    for (int mi = 0; mi < 4; ++mi)
        aRow[mi] = &Als[(wr * 128 + mi * 32 + m31) * 64];
    #pragma unroll
    for (int ni = 0; ni < 2; ++ni)
        bRow[ni] = &Bls[(wc * 64 + ni * 32 + m31) * 64];
    int segoff[4];
    #pragma unroll
    for (int t = 0; t < 4; ++t)
        segoff[t] = ((t * 2 + hi) ^ r7) * 8;

    for (int k0 = 0; k0 < KDIM; k0 += 64) {
        #pragma unroll
        for (int i = 0; i < 8; ++i)
            async16(Abase + k0 + (size_t)(i * 32) * KDIM, AldsU + i * 32 * 64);
        #pragma unroll
        for (int j = 0; j < 4; ++j)
            async16(Bbase + k0 + (size_t)(j * 32) * KDIM, BldsU + j * 32 * 64);
        __syncthreads();

        #pragma unroll
        for (int t = 0; t < 4; ++t) {
            bf16x8 af[4], bfv[2];
            #pragma unroll
            for (int mi = 0; mi < 4; ++mi)
                af[mi] = *(const bf16x8*)(aRow[mi] + segoff[t]);
            #pragma unroll
            for (int ni = 0; ni < 2; ++ni)
                bfv[ni] = *(const bf16x8*)(bRow[ni] + segoff[t]);
            #pragma unroll
            for (int mi = 0; mi < 4; ++mi)
                #pragma unroll
                for (int ni = 0; ni < 2; ++ni)
                    acc[mi][ni] = __builtin_amdgcn_mfma_f32_32x32x16_bf16(
                        af[mi], bfv[ni], acc[mi][ni], 0, 0, 0);
        }
        __syncthreads();
    }

    // ---- epilogue: 32x32 C/D layout: col=lane&31,
    // row = (reg&3) + 8*(reg>>2) + 4*(lane>>5) ----
    const int colg = bn * 128 + wc * 64 + m31;
    float bv[2] = { bias[colg], bias[colg + 32] };
    #pragma unroll
    for (int mi = 0; mi < 4; ++mi) {
        #pragma unroll
        for (int r = 0; r < 16; ++r) {
            int row = bm * 256 + wr * 128 + mi * 32 + (r & 3) + 8 * (r >> 2) + 4 * hi;
            size_t grow = (size_t)row * NDIM;
            C[grow + colg]      = f2bf(acc[mi][0][r] + bv[0]);
            C[grow + colg + 32] = f2bf(acc[mi][1][r] + bv[1]);
        }
    }
}

// ---------------------------------------------------------------------------
// fused LN(hi)+LN(hh)+gates+LN(cell)+outputs. TWO rows per block:
// sub = tid>>7 selects row, t = tid&127 covers 8 cols per gate (16B loads).
// ---------------------------------------------------------------------------
__global__ __launch_bounds__(256) void ln_gates(
    const unsigned short* __restrict__ hi_pre, const unsigned short* __restrict__ hh_pre,
    const float* __restrict__ c_prev,
    const float* __restrict__ g1, const float* __restrict__ be1,
    const float* __restrict__ g2, const float* __restrict__ be2,
    const float* __restrict__ gc, const float* __restrict__ bec,
    float* __restrict__ h_out, float* __restrict__ c_out)
{
    __shared__ float sm[16];
    const int tid = threadIdx.x;
    const int sub = tid >> 7, t = tid & 127;
    const int wv = tid >> 6, lane = tid & 63;
    const int row = blockIdx.x * 2 + sub;
    const unsigned short* hir = hi_pre + (size_t)row * NDIM;
    const unsigned short* hhr = hh_pre + (size_t)row * NDIM;

    u16x8 vi[4], vh[4];
    float s1 = 0.f, ss1 = 0.f, s2 = 0.f, ss2 = 0.f;
    #pragma unroll
    for (int q = 0; q < 4; ++q) {
        int col = q * 1024 + t * 8;
        vi[q] = *(const u16x8*)(hir + col);
        vh[q] = *(const u16x8*)(hhr + col);
        #pragma unroll
        for (int j = 0; j < 8; ++j) {
            float a = bf2f(vi[q][j]), b = bf2f(vh[q][j]);
            s1 += a; ss1 += a * a; s2 += b; ss2 += b * b;
        }
    }
    #pragma unroll
    for (int off = 32; off > 0; off >>= 1) {
        s1 += __shfl_down(s1, off, 64);
        ss1 += __shfl_down(ss1, off, 64);
        s2 += __shfl_down(s2, off, 64);
        ss2 += __shfl_down(ss2, off, 64);
    }
    if (lane == 0) {
        sm[wv * 4 + 0] = s1; sm[wv * 4 + 1] = ss1;
        sm[wv * 4 + 2] = s2; sm[wv * 4 + 3] = ss2;
    }
    __syncthreads();
    const int base = sub * 8;
    float R1 = sm[base + 0] + sm[base + 4];
    float Q1 = sm[base + 1] + sm[base + 5];
    float R2 = sm[base + 2] + sm[base + 6];
    float Q2 = sm[base + 3] + sm[base + 7];

    const float n1 = (float)NDIM;
    float m1 = R1 / n1;
    float v1 = (Q1 - n1 * m1 * m1) / (n1 - 1.f);
    float r1 = 1.0f / (sqrtf(fmaxf(v1, 0.f)) + EPSV);
    float m2 = R2 / n1;
    float v2 = (Q2 - n1 * m2 * m2) / (n1 - 1.f);
    float r2 = 1.0f / (sqrtf(fmaxf(v2, 0.f)) + EPSV);

    float gate[4][8];
    #pragma unroll
    for (int q = 0; q < 4; ++q) {
        int col = q * 1024 + t * 8;
        float4 G1a = *(const float4*)(g1 + col),  G1b = *(const float4*)(g1 + col + 4);
        float4 B1a = *(const float4*)(be1 + col), B1b = *(const float4*)(be1 + col + 4);
        float4 G2a = *(const float4*)(g2 + col),  G2b = *(const float4*)(g2 + col + 4);
        float4 B2a = *(const float4*)(be2 + col), B2b = *(const float4*)(be2 + col + 4);
        float G1[8] = {G1a.x, G1a.y, G1a.z, G1a.w, G1b.x, G1b.y, G1b.z, G1b.w};
        float B1[8] = {B1a.x, B1a.y, B1a.z, B1a.w, B1b.x, B1b.y, B1b.z, B1b.w};
        float G2[8] = {G2a.x, G2a.y, G2a.z, G2a.w, G2b.x, G2b.y, G2b.z, G2b.w};
        float B2[8] = {B2a.x, B2a.y, B2a.z, B2a.w, B2b.x, B2b.y, B2b.z, B2b.w};
        #pragma unroll
        for (int j = 0; j < 8; ++j)
            gate[q][j] = G1[j] * (bf2f(vi[q][j]) - m1) * r1 + B1[j]
                       + G2[j] * (bf2f(vh[q][j]) - m2) * r2 + B2[j];
    }

    float4 cpa = *(const float4*)(c_prev + (size_t)row * 1024 + t * 8);
    float4 cpb = *(const float4*)(c_prev + (size_t)row * 1024 + t * 8 + 4);
    float cpv[8] = {cpa.x, cpa.y, cpa.z, cpa.w, cpb.x, cpb.y, cpb.z, cpb.w};
    float a[8];
    float s3 = 0.f, ss3 = 0.f;
    #pragma unroll
    for (int j = 0; j < 8; ++j) {
        a[j] = cpv[j] * sigm(gate[1][j] + 1.0f) + ftanh(gate[2][j]) * sigm(gate[0][j]);
        s3 += a[j]; ss3 += a[j] * a[j];
    }
    #pragma unroll
    for (int off = 32; off > 0; off >>= 1) {
        s3 += __shfl_down(s3, off, 64);
        ss3 += __shfl_down(ss3, off, 64);
    }
    __syncthreads();   // sm reuse
    if (lane == 0) { sm[wv * 2 + 0] = s3; sm[wv * 2 + 1] = ss3; }
    __syncthreads();
    const int b2 = sub * 4;
    float R3 = sm[b2 + 0] + sm[b2 + 2];
    float Q3 = sm[b2 + 1] + sm[b2 + 3];
    const float n3 = 1024.f;
    float m3 = R3 / n3;
    float v3 = (Q3 - n3 * m3 * m3) / (n3 - 1.f);
    float r3 = 1.0f / (sqrtf(fmaxf(v3, 0.f)) + EPSV);

    int colh = t * 8;
    float4 GCa = *(const float4*)(gc + colh),  GCb = *(const float4*)(gc + colh + 4);
    float4 BCa = *(const float4*)(bec + colh), BCb = *(const float4*)(bec + colh + 4);
    float GC[8] = {GCa.x, GCa.y, GCa.z, GCa.w, GCb.x, GCb.y, GCb.z, GCb.w};
    float BC[8] = {BCa.x, BCa.y, BCa.z, BCa.w, BCb.x, BCb.y, BCb.z, BCb.w};
    float cj[8], hj[8];
    #pragma unroll
    for (int j = 0; j < 8; ++j) {
        cj[j] = GC[j] * (a[j] - m3) * r3 + BC[j];
        hj[j] = sigm(gate[3][j]) * ftanh(cj[j]);
    }
    float4 hva = {hj[0], hj[1], hj[2], hj[3]}, hvb = {hj[4], hj[5], hj[6], hj[7]};
    float4 cva = {cj[0], cj[1], cj[2], cj[3]}, cvb = {cj[4], cj[5], cj[6], cj[7]};
    *(float4*)(h_out + (size_t)row * 1024 + colh) = hva;
    *(float4*)(h_out + (size_t)row * 1024 + colh + 4) = hvb;
    *(float4*)(c_out + (size_t)row * 1024 + colh) = cva;
    *(float4*)(c_out + (size_t)row * 1024 + colh + 4) = cvb;
}

// ---------------------------------------------------------------------------
extern "C" void kernel_launch(void* const* d_in, const int* in_sizes, int n_in,
                              void* d_out, int out_size, void* d_ws, size_t ws_size,
                              hipStream_t stream) {
    const float* input  = (const float*)d_in[0];
    const float* h_prev = (const float*)d_in[1];
    const float* c_prev = (const float*)d_in[2];
    const float* w_i2h  = (const float*)d_in[3];
    const float* b_i2h  = (const float*)d_in[4];
    const float* w_h2h  = (const float*)d_in[5];
    const float* b_h2h  = (const float*)d_in[6];
    const float* g_i2h  = (const float*)d_in[7];
    const float* be_i2h = (const float*)d_in[8];
    const float* g_h2h  = (const float*)d_in[9];
    const float* be_h2h = (const float*)d_in[10];
    const float* g_c    = (const float*)d_in[11];
    const float* be_c   = (const float*)d_in[12];

    const size_t MK = (size_t)BDIM * KDIM;       // 4M
    const size_t MN = (size_t)BDIM * NDIM;       // 16M

    unsigned short* inA    = (unsigned short*)d_ws;
    unsigned short* inH    = inA + MK;
    unsigned short* w1T    = inH + MK;           // [N][K]
    unsigned short* w2T    = w1T + MK;
    unsigned short* hi_pre = w2T + MK;           // [B][4H] bf16
    unsigned short* hh_pre = hi_pre + MN;        // total 96 MB

    float* h_out = (float*)d_out;
    float* c_out = h_out + (size_t)BDIM * 1024;

    prep<<<dim3(2048, 1, 4), 256, 0, stream>>>(
        input, inA, h_prev, inH, w_i2h, w1T, w_h2h, w2T);

    gemm_bias_bf16<<<dim3(16, 32, 2), 256, 0, stream>>>(
        inA, w1T, b_i2h, hi_pre, inH, w2T, b_h2h, hh_pre);

    ln_gates<<<2048, 256, 0, stream>>>(
        hi_pre, hh_pre, c_prev, g_i2h, be_i2h, g_h2h, be_h2h, g_c, be_c, h_out, c_out);
}

// Round 6
// 237.656 us; speedup vs baseline: 1.1057x; 1.0309x over previous
//
#include <hip/hip_runtime.h>
#include <hip/hip_bf16.h>
#include <stdint.h>

// ---------------------------------------------------------------------------
// LayerNormLSTMCell: B=4096, I=H=1024, 4H=4096
//  hi = LN(input @ w_i2h + b_i2h; g_i2h, be_i2h)        [B,4H]
//  hh = LN(h_prev @ w_h2h + b_h2h; g_h2h, be_h2h)       [B,4H]
//  i,f,u,o = split(hi+hh, 4)
//  c = LN(c_prev*sigm(f+1) + tanh(u)*sigm(i); g_c,be_c) [B,H]
//  h = sigm(o)*tanh(c)
// LN: mean, UNBIASED std (ddof=1), divide by (std + 1e-6)
// ---------------------------------------------------------------------------

#define BDIM 4096
#define KDIM 1024
#define NDIM 4096
#define EPSV 1e-6f

typedef float f32x4 __attribute__((ext_vector_type(4)));
typedef __bf16 bf16x8 __attribute__((ext_vector_type(8)));
typedef unsigned short u16x8 __attribute__((ext_vector_type(8)));

__device__ inline unsigned short f2bf(float f) {
    unsigned u = __builtin_bit_cast(unsigned, f);
    u += 0x7FFFu + ((u >> 16) & 1u);   // round-to-nearest-even
    return (unsigned short)(u >> 16);
}
__device__ inline float bf2f(unsigned short u) {
    return __builtin_bit_cast(float, (unsigned)u << 16);
}
__device__ inline float sigm(float x) {
    return 1.0f / (1.0f + __expf(-x));
}
// fast tanh: 1 - 2/(e^{2x}+1); saturates correctly at +-inf
__device__ inline float ftanh(float x) {
    return 1.0f - 2.0f / (__expf(2.0f * x) + 1.0f);
}

// async global->LDS, 16B per lane. lds ptr must be wave-uniform.
__device__ inline void async16(const unsigned short* g, unsigned short* lds) {
    __builtin_amdgcn_global_load_lds(
        (const __attribute__((address_space(1))) void*)g,
        (__attribute__((address_space(3))) void*)lds,
        16, 0, 0);
}

// ---------------------------------------------------------------------------
// prep: z=0/1 cast input/h_prev f32->bf16 (8 elem/thread, 16B stores)
//       z=2/3 transpose+cast w f32 [1024][4096] -> bf16 [4096][1024]
// ---------------------------------------------------------------------------
__global__ __launch_bounds__(256) void prep(
    const float* __restrict__ in0, unsigned short* __restrict__ o0,
    const float* __restrict__ in1, unsigned short* __restrict__ o1,
    const float* __restrict__ w0, unsigned short* __restrict__ w0T,
    const float* __restrict__ w1, unsigned short* __restrict__ w1T)
{
    __shared__ float tile[64][65];
    const int z = blockIdx.z, tid = threadIdx.x;
    if (z < 2) {
        const float* src = z ? in1 : in0;
        unsigned short* dst = z ? o1 : o0;
        int i = (blockIdx.x * 256 + tid) * 8;
        float4 a = *(const float4*)(src + i);
        float4 b = *(const float4*)(src + i + 4);
        u16x8 v;
        v[0] = f2bf(a.x); v[1] = f2bf(a.y); v[2] = f2bf(a.z); v[3] = f2bf(a.w);
        v[4] = f2bf(b.x); v[5] = f2bf(b.y); v[6] = f2bf(b.z); v[7] = f2bf(b.w);
        *(u16x8*)(dst + i) = v;
        return;
    }
    const int bx = blockIdx.x;
    if (bx >= (NDIM / 64) * (KDIM / 64)) return;
    const float* src = (z == 3) ? w1 : w0;
    unsigned short* dst = (z == 3) ? w1T : w0T;
    const int c0 = (bx & (NDIM / 64 - 1)) * 64;   // col in [0,4096)
    const int r0 = (bx >> 6) * 64;                // row in [0,1024)
    const int tx = tid & 63, ty = tid >> 6;       // 64 x 4
    #pragma unroll
    for (int i = 0; i < 64; i += 4)
        tile[ty + i][tx] = src[(size_t)(r0 + ty + i) * NDIM + c0 + tx];
    __syncthreads();
    #pragma unroll
    for (int p = 0; p < 2; ++p) {
        int c = p * 32 + (tid >> 3);
        int rs = (tid & 7) * 8;
        u16x8 v;
        #pragma unroll
        for (int j = 0; j < 8; ++j) v[j] = f2bf(tile[rs + j][c]);
        *(u16x8*)(dst + (size_t)(c0 + c) * KDIM + r0 + rs) = v;
    }
}

// ---------------------------------------------------------------------------
// GEMM: C[m][n] = sum_k A[m][k] * Bt[n][k] + bias[n]   (bf16 in, bf16 out)
// M=4096 N=4096 K=1024. Block tile 256x128, BK=64, 4 waves in 2x2 grid,
// wave-tile 128x64 via 8x4 of 16x16x32 MFMA (acc 128 regs/lane).
// The 16x16 fragment read pattern (rows lane&15, phys seg = (s*4+q)^r7)
// measured ZERO bank conflicts in R4; the 32x32 pattern measured 6.29M (R5)
// -> keep 16x16 reads with the big tile. LDS: A 32KB + B 16KB.
// blockIdx.z selects problem (i2h vs h2h).
// ---------------------------------------------------------------------------
__global__ __launch_bounds__(256, 2) void gemm_bias_bf16(
    const unsigned short* __restrict__ A0, const unsigned short* __restrict__ B0,
    const float* __restrict__ bias0, unsigned short* __restrict__ C0,
    const unsigned short* __restrict__ A1, const unsigned short* __restrict__ B1,
    const float* __restrict__ bias1, unsigned short* __restrict__ C1)
{
    const unsigned short* A  = blockIdx.z ? A1 : A0;
    const unsigned short* Bt = blockIdx.z ? B1 : B0;
    const float* bias        = blockIdx.z ? bias1 : bias0;
    unsigned short* C        = blockIdx.z ? C1 : C0;

    __shared__ __align__(16) unsigned short Als[256 * 64];   // 32 KB
    __shared__ __align__(16) unsigned short Bls[128 * 64];   // 16 KB

    const int tid  = threadIdx.x;
    const int wid  = tid >> 6;
    const int lane = tid & 63;
    const int bm = blockIdx.x;      // 0..15 (256-row tiles)
    const int bn = blockIdx.y;      // 0..31 (128-col tiles)

    const int wr = wid >> 1;        // wave row: rows wr*128
    const int wc = wid & 1;         // wave col: cols wc*64

    f32x4 acc[8][4] = {};

    // ---- staging: each async16 covers 32 rows (8/wave); row = base+(lane>>3),
    // global k-seg XOR-swizzled: sseg = (lane&7)^(row&7), row&7 = lane>>3 ----
    const int sseg = (lane & 7) ^ (lane >> 3);
    const unsigned short* Abase =
        A + (size_t)(bm * 256 + wid * 8 + (lane >> 3)) * KDIM + sseg * 8;
    const unsigned short* Bbase =
        Bt + (size_t)(bn * 128 + wid * 8 + (lane >> 3)) * KDIM + sseg * 8;
    unsigned short* AldsU = Als + (wid * 8) * 64;   // wave-uniform
    unsigned short* BldsU = Bls + (wid * 8) * 64;

    // ---- fragment addressing (16x16x32, R4-proven conflict-free):
    // frag row = base + mi*16 + (lane&15); row&7 = lane&7 = r7
    // logical k-seg = s*4 + q (q = lane>>4); phys = logical ^ r7 ----
    const int q    = lane >> 4;
    const int r7   = lane & 7;
    const int frow = lane & 15;
    const unsigned short* aRow[8];
    const unsigned short* bRow[4];
    #pragma unroll
    for (int mi = 0; mi < 8; ++mi)
        aRow[mi] = &Als[(wr * 128 + mi * 16 + frow) * 64];
    #pragma unroll
    for (int ni = 0; ni < 4; ++ni)
        bRow[ni] = &Bls[(wc * 64 + ni * 16 + frow) * 64];
    const int ph0 = ((q ^ r7)) * 8;        // k-seg 0 (s=0)
    const int ph1 = ((q ^ r7) ^ 4) * 8;    // k-seg 1 (s=1; s*4 flips bit 2)

    for (int k0 = 0; k0 < KDIM; k0 += 64) {
        #pragma unroll
        for (int i = 0; i < 8; ++i)
            async16(Abase + k0 + (size_t)(i * 32) * KDIM, AldsU + i * 32 * 64);
        #pragma unroll
        for (int j = 0; j < 4; ++j)
            async16(Bbase + k0 + (size_t)(j * 32) * KDIM, BldsU + j * 32 * 64);
        __syncthreads();

        #pragma unroll
        for (int s = 0; s < 2; ++s) {
            const int ph = s ? ph1 : ph0;
            bf16x8 af[8], bfv[4];
            #pragma unroll
            for (int mi = 0; mi < 8; ++mi)
                af[mi] = *(const bf16x8*)(aRow[mi] + ph);
            #pragma unroll
            for (int ni = 0; ni < 4; ++ni)
                bfv[ni] = *(const bf16x8*)(bRow[ni] + ph);
            #pragma unroll
            for (int mi = 0; mi < 8; ++mi)
                #pragma unroll
                for (int ni = 0; ni < 4; ++ni)
                    acc[mi][ni] = __builtin_amdgcn_mfma_f32_16x16x32_bf16(
                        af[mi], bfv[ni], acc[mi][ni], 0, 0, 0);
        }
        __syncthreads();
    }

    // ---- epilogue (R2-proven 16x16 layout): D[row=(lane>>4)*4+r][col=lane&15]
    const int rb = wr * 128 + (lane >> 4) * 4;
    const int cb = wc * 64 + (lane & 15);
    float bv[4];
    #pragma unroll
    for (int ni = 0; ni < 4; ++ni) bv[ni] = bias[bn * 128 + cb + ni * 16];
    #pragma unroll
    for (int mi = 0; mi < 8; ++mi) {
        #pragma unroll
        for (int r = 0; r < 4; ++r) {
            size_t grow = (size_t)(bm * 256 + rb + mi * 16 + r) * NDIM;
            #pragma unroll
            for (int ni = 0; ni < 4; ++ni)
                C[grow + bn * 128 + cb + ni * 16] = f2bf(acc[mi][ni][r] + bv[ni]);
        }
    }
}

// ---------------------------------------------------------------------------
// fused LN(hi)+LN(hh)+gates+LN(cell)+outputs. TWO rows per block:
// sub = tid>>7 selects row, t = tid&127 covers 8 cols per gate (16B loads).
// ---------------------------------------------------------------------------
__global__ __launch_bounds__(256) void ln_gates(
    const unsigned short* __restrict__ hi_pre, const unsigned short* __restrict__ hh_pre,
    const float* __restrict__ c_prev,
    const float* __restrict__ g1, const float* __restrict__ be1,
    const float* __restrict__ g2, const float* __restrict__ be2,
    const float* __restrict__ gc, const float* __restrict__ bec,
    float* __restrict__ h_out, float* __restrict__ c_out)
{
    __shared__ float sm[16];
    const int tid = threadIdx.x;
    const int sub = tid >> 7, t = tid & 127;
    const int wv = tid >> 6, lane = tid & 63;
    const int row = blockIdx.x * 2 + sub;
    const unsigned short* hir = hi_pre + (size_t)row * NDIM;
    const unsigned short* hhr = hh_pre + (size_t)row * NDIM;

    u16x8 vi[4], vh[4];
    float s1 = 0.f, ss1 = 0.f, s2 = 0.f, ss2 = 0.f;
    #pragma unroll
    for (int q = 0; q < 4; ++q) {
        int col = q * 1024 + t * 8;
        vi[q] = *(const u16x8*)(hir + col);
        vh[q] = *(const u16x8*)(hhr + col);
        #pragma unroll
        for (int j = 0; j < 8; ++j) {
            float a = bf2f(vi[q][j]), b = bf2f(vh[q][j]);
            s1 += a; ss1 += a * a; s2 += b; ss2 += b * b;
        }
    }
    #pragma unroll
    for (int off = 32; off > 0; off >>= 1) {
        s1 += __shfl_down(s1, off, 64);
        ss1 += __shfl_down(ss1, off, 64);
        s2 += __shfl_down(s2, off, 64);
        ss2 += __shfl_down(ss2, off, 64);
    }
    if (lane == 0) {
        sm[wv * 4 + 0] = s1; sm[wv * 4 + 1] = ss1;
        sm[wv * 4 + 2] = s2; sm[wv * 4 + 3] = ss2;
    }
    __syncthreads();
    const int base = sub * 8;
    float R1 = sm[base + 0] + sm[base + 4];
    float Q1 = sm[base + 1] + sm[base + 5];
    float R2 = sm[base + 2] + sm[base + 6];
    float Q2 = sm[base + 3] + sm[base + 7];

    const float n1 = (float)NDIM;
    float m1 = R1 / n1;
    float v1 = (Q1 - n1 * m1 * m1) / (n1 - 1.f);
    float r1 = 1.0f / (sqrtf(fmaxf(v1, 0.f)) + EPSV);
    float m2 = R2 / n1;
    float v2 = (Q2 - n1 * m2 * m2) / (n1 - 1.f);
    float r2 = 1.0f / (sqrtf(fmaxf(v2, 0.f)) + EPSV);

    float gate[4][8];
    #pragma unroll
    for (int q = 0; q < 4; ++q) {
        int col = q * 1024 + t * 8;
        float4 G1a = *(const float4*)(g1 + col),  G1b = *(const float4*)(g1 + col + 4);
        float4 B1a = *(const float4*)(be1 + col), B1b = *(const float4*)(be1 + col + 4);
        float4 G2a = *(const float4*)(g2 + col),  G2b = *(const float4*)(g2 + col + 4);
        float4 B2a = *(const float4*)(be2 + col), B2b = *(const float4*)(be2 + col + 4);
        float G1[8] = {G1a.x, G1a.y, G1a.z, G1a.w, G1b.x, G1b.y, G1b.z, G1b.w};
        float B1[8] = {B1a.x, B1a.y, B1a.z, B1a.w, B1b.x, B1b.y, B1b.z, B1b.w};
        float G2[8] = {G2a.x, G2a.y, G2a.z, G2a.w, G2b.x, G2b.y, G2b.z, G2b.w};
        float B2[8] = {B2a.x, B2a.y, B2a.z, B2a.w, B2b.x, B2b.y, B2b.z, B2b.w};
        #pragma unroll
        for (int j = 0; j < 8; ++j)
            gate[q][j] = G1[j] * (bf2f(vi[q][j]) - m1) * r1 + B1[j]
                       + G2[j] * (bf2f(vh[q][j]) - m2) * r2 + B2[j];
    }

    float4 cpa = *(const float4*)(c_prev + (size_t)row * 1024 + t * 8);
    float4 cpb = *(const float4*)(c_prev + (size_t)row * 1024 + t * 8 + 4);
    float cpv[8] = {cpa.x, cpa.y, cpa.z, cpa.w, cpb.x, cpb.y, cpb.z, cpb.w};
    float a[8];
    float s3 = 0.f, ss3 = 0.f;
    #pragma unroll
    for (int j = 0; j < 8; ++j) {
        a[j] = cpv[j] * sigm(gate[1][j] + 1.0f) + ftanh(gate[2][j]) * sigm(gate[0][j]);
        s3 += a[j]; ss3 += a[j] * a[j];
    }
    #pragma unroll
    for (int off = 32; off > 0; off >>= 1) {
        s3 += __shfl_down(s3, off, 64);
        ss3 += __shfl_down(ss3, off, 64);
    }
    __syncthreads();   // sm reuse
    if (lane == 0) { sm[wv * 2 + 0] = s3; sm[wv * 2 + 1] = ss3; }
    __syncthreads();
    const int b2 = sub * 4;
    float R3 = sm[b2 + 0] + sm[b2 + 2];
    float Q3 = sm[b2 + 1] + sm[b2 + 3];
    const float n3 = 1024.f;
    float m3 = R3 / n3;
    float v3 = (Q3 - n3 * m3 * m3) / (n3 - 1.f);
    float r3 = 1.0f / (sqrtf(fmaxf(v3, 0.f)) + EPSV);

    int colh = t * 8;
    float4 GCa = *(const float4*)(gc + colh),  GCb = *(const float4*)(gc + colh + 4);
    float4 BCa = *(const float4*)(bec + colh), BCb = *(const float4*)(bec + colh + 4);
    float GC[8] = {GCa.x, GCa.y, GCa.z, GCa.w, GCb.x, GCb.y, GCb.z, GCb.w};
    float BC[8] = {BCa.x, BCa.y, BCa.z, BCa.w, BCb.x, BCb.y, BCb.z, BCb.w};
    float cj[8], hj[8];
    #pragma unroll
    for (int j = 0; j < 8; ++j) {
        cj[j] = GC[j] * (a[j] - m3) * r3 + BC[j];
        hj[j] = sigm(gate[3][j]) * ftanh(cj[j]);
    }
    float4 hva = {hj[0], hj[1], hj[2], hj[3]}, hvb = {hj[4], hj[5], hj[6], hj[7]};
    float4 cva = {cj[0], cj[1], cj[2], cj[3]}, cvb = {cj[4], cj[5], cj[6], cj[7]};
    *(float4*)(h_out + (size_t)row * 1024 + colh) = hva;
    *(float4*)(h_out + (size_t)row * 1024 + colh + 4) = hvb;
    *(float4*)(c_out + (size_t)row * 1024 + colh) = cva;
    *(float4*)(c_out + (size_t)row * 1024 + colh + 4) = cvb;
}

// ---------------------------------------------------------------------------
extern "C" void kernel_launch(void* const* d_in, const int* in_sizes, int n_in,
                              void* d_out, int out_size, void* d_ws, size_t ws_size,
                              hipStream_t stream) {
    const float* input  = (const float*)d_in[0];
    const float* h_prev = (const float*)d_in[1];
    const float* c_prev = (const float*)d_in[2];
    const float* w_i2h  = (const float*)d_in[3];
    const float* b_i2h  = (const float*)d_in[4];
    const float* w_h2h  = (const float*)d_in[5];
    const float* b_h2h  = (const float*)d_in[6];
    const float* g_i2h  = (const float*)d_in[7];
    const float* be_i2h = (const float*)d_in[8];
    const float* g_h2h  = (const float*)d_in[9];
    const float* be_h2h = (const float*)d_in[10];
    const float* g_c    = (const float*)d_in[11];
    const float* be_c   = (const float*)d_in[12];

    const size_t MK = (size_t)BDIM * KDIM;       // 4M
    const size_t MN = (size_t)BDIM * NDIM;       // 16M

    unsigned short* inA    = (unsigned short*)d_ws;
    unsigned short* inH    = inA + MK;
    unsigned short* w1T    = inH + MK;           // [N][K]
    unsigned short* w2T    = w1T + MK;
    unsigned short* hi_pre = w2T + MK;           // [B][4H] bf16
    unsigned short* hh_pre = hi_pre + MN;        // total 96 MB

    float* h_out = (float*)d_out;
    float* c_out = h_out + (size_t)BDIM * 1024;

    prep<<<dim3(2048, 1, 4), 256, 0, stream>>>(
        input, inA, h_prev, inH, w_i2h, w1T, w_h2h, w2T);

    gemm_bias_bf16<<<dim3(16, 32, 2), 256, 0, stream>>>(
        inA, w1T, b_i2h, hi_pre, inH, w2T, b_h2h, hh_pre);

    ln_gates<<<2048, 256, 0, stream>>>(
        hi_pre, hh_pre, c_prev, g_i2h, be_i2h, g_h2h, be_h2h, g_c, be_c, h_out, c_out);
}